// Round 1
// baseline (164.718 us; speedup 1.0000x reference)
//
#include <hip/hip_runtime.h>

// Problem: out[b,c,h,w] = x[b,c,h,w] + circle_mats[dist(h,w), c]
// x: (8, 768, 8, 2048) fp32, circle_mats: (4, 768) fp32
// dist = min(h, w, 7-h, 2047-w) in [0,3]. For 3 <= w <= 2044, dist = min(h,7-h).
// Pure streaming memory-bound op: ~805 MB HBM traffic, roofline ~128 us.

#define W_DIM 2048
#define H_DIM 8
#define C_DIM 768

__global__ __launch_bounds__(256) void circle_add_kernel(
    const float4* __restrict__ x, const float* __restrict__ cm,
    float4* __restrict__ out, int total4) {
  const int stride = gridDim.x * blockDim.x;
  for (int idx = blockIdx.x * blockDim.x + threadIdx.x; idx < total4;
       idx += stride) {
    const int e  = idx << 2;              // first element index (fits in int: ~1e8)
    const int w0 = e & (W_DIM - 1);       // column of first element (multiple of 4)
    const int hw = e >> 11;               // = (b*C + c)*H + h
    const int h  = hw & (H_DIM - 1);
    const int bc = hw >> 3;               // = b*C + c
    const int c  = bc - (bc / C_DIM) * C_DIM;
    const int di = min(h, (H_DIM - 1) - h);   // row-limited dist, 0..3

    const float base = cm[di * C_DIM + c];    // L1-resident (12 KB table)
    float4 xv = x[idx];
    float4 av = {base, base, base, base};

    // Edge columns: only the first and last float4 of each row differ.
    if (w0 == 0) {
      av.x = cm[c];                            // dist = 0
      av.y = cm[min(di, 1) * C_DIM + c];
      av.z = cm[min(di, 2) * C_DIM + c];
      // w=3: dist = min(di,3) = di  (di <= 3)
    } else if (w0 == W_DIM - 4) {
      // w = 2044,2045,2046,2047 -> 2047-w = 3,2,1,0
      av.y = cm[min(di, 2) * C_DIM + c];
      av.z = cm[min(di, 1) * C_DIM + c];
      av.w = cm[c];                            // dist = 0
    }

    float4 ov;
    ov.x = xv.x + av.x;
    ov.y = xv.y + av.y;
    ov.z = xv.z + av.z;
    ov.w = xv.w + av.w;
    out[idx] = ov;
  }
}

extern "C" void kernel_launch(void* const* d_in, const int* in_sizes, int n_in,
                              void* d_out, int out_size, void* d_ws, size_t ws_size,
                              hipStream_t stream) {
  const float* x  = (const float*)d_in[0];
  const float* cm = (const float*)d_in[1];
  float* out = (float*)d_out;

  const int total4 = out_size / 4;  // 100,663,296 / 4 = 25,165,824 float4s
  const int block = 256;
  const int grid = 2048;            // 8 blocks/CU * 256 CU; grid-stride covers rest

  circle_add_kernel<<<grid, block, 0, stream>>>(
      (const float4*)x, cm, (float4*)out, total4);
}